// Round 1
// 611.676 us; speedup vs baseline: 1.2511x; 1.2511x over previous
//
#include <hip/hip_runtime.h>

// LightGCN, atomic-free CSR build (bucketed counting sort) + bf16 g-form layers.
//
// Build pipeline (replaces k_count/k_offsets/k_scatter/k_dinv, no memset):
//   k_bucket_count   : 1024 blocks x disjoint edge ranges, LDS hist over
//                      586 node-buckets (256 nodes each), dump bh[k][b].
//   k_scan_blocks    : per-bucket exclusive scan over the 1024 block counts
//                      (in-place in bh) + bucket totals.
//   k_scan_buckets   : exclusive scan of bucket totals -> bucket CSR bases.
//   k_bucket_scatter : re-stream same edge ranges, LDS cursors preloaded with
//                      scanned bases, place packed {row_local|col<<8, v} 8B
//                      entries into per-bucket regions (cap CAP).
//   k_bucket_csr     : one block per bucket: LDS 256-bin hist + LDS float deg
//                      accumulation + LDS scan -> offs/cnt/dinv/dsq, then
//                      scatter final csr {col, v} (bucket-local destinations).
// Rationale: device-scope atomics write through the non-coherent per-XCD L2s
// (k_count showed 140MB WRITE_SIZE for 4M atomics, 190us). Within-row entry
// order was already nondeterministic, so a deterministic bucket sort with LDS
// aggregation needs ZERO global atomics.
//
// Bucket staging (NB*CAP*8 ~ 75MB) aliases g[1..4] (dead until layer 0).
//
// g-form: g = dinv(*)e; s_r = sum v*g_c; g' = dinv_r^2 * s_r.
// k_final reconstructs acc = e0 + sum_l dsq*g_l (dsq = sqrt(deg)).

static inline size_t align_up(size_t x, size_t a) { return (x + a - 1) & ~(a - 1); }

#define NBA 640          // max buckets (N <= 163840); N = 150000 -> NB = 586
#define KB  1024         // edge-range blocks for count/scatter passes

__device__ inline unsigned short f32_to_bf16(float f) {
    unsigned int u = __float_as_uint(f);
    unsigned int r = (u + 0x7FFFu + ((u >> 16) & 1u)) >> 16;   // RNE
    return (unsigned short)r;
}
__device__ inline float bf16_to_f32(unsigned short h) {
    return __uint_as_float(((unsigned int)h) << 16);
}

// 1024 blocks, block k owns edges [k*CH, min(E,(k+1)*CH)).
// LDS histogram over node-buckets (node>>8); dump bh[k*NBA + b] (coalesced).
__global__ __launch_bounds__(256) void k_bucket_count(
        const int* __restrict__ eu, const int* __restrict__ ei,
        int* __restrict__ bh, int U, int E, int NB, int CH) {
    __shared__ int hist[NBA];
    int k = blockIdx.x;
    int t = threadIdx.x;
    for (int b = t; b < NBA; b += 256) hist[b] = 0;
    __syncthreads();
    int lo = k * CH, hi = min(E, lo + CH);
    for (int i = lo + t; i < hi; i += 256) {
        int u  = eu[i];
        int it = ei[i] + U;
        atomicAdd(&hist[u >> 8], 1);
        atomicAdd(&hist[it >> 8], 1);
    }
    __syncthreads();
    for (int b = t; b < NB; b += 256) bh[k * NBA + b] = hist[b];
}

// One block per bucket b: exclusive scan (in place) of bh[k][b] over k=0..1023,
// total[b] = sum. 256 threads x 4 sequential elements each.
__global__ __launch_bounds__(256) void k_scan_blocks(
        int* __restrict__ bh, int* __restrict__ total, int NB) {
    __shared__ int s[256];
    int b = blockIdx.x;
    int t = threadIdx.x;
    int k0 = t * 4;
    int vals[4];
    int sum = 0;
    #pragma unroll
    for (int j = 0; j < 4; ++j) { vals[j] = bh[(k0 + j) * NBA + b]; sum += vals[j]; }
    s[t] = sum;
    __syncthreads();
    for (int d = 1; d < 256; d <<= 1) {
        int v = (t >= d) ? s[t - d] : 0;
        __syncthreads();
        s[t] += v;
        __syncthreads();
    }
    int run = s[t] - sum;            // exclusive base for this thread's chunk
    #pragma unroll
    for (int j = 0; j < 4; ++j) { int v = vals[j]; bh[(k0 + j) * NBA + b] = run; run += v; }
    if (t == 255) total[b] = run;
}

// Single block: exclusive scan of bucket totals -> bucket CSR/entry bases.
__global__ __launch_bounds__(256) void k_scan_buckets(
        const int* __restrict__ total, int* __restrict__ bbase, int NB) {
    __shared__ int s[256];
    int t = threadIdx.x;
    int C = (NB + 255) / 256;        // <= 3 for NB <= 640 (vals[4] headroom)
    int vals[4];
    int sum = 0;
    for (int j = 0; j < C; ++j) {
        int idx = t * C + j;
        int v = (idx < NB) ? total[idx] : 0;
        vals[j] = v; sum += v;
    }
    s[t] = sum;
    __syncthreads();
    for (int d = 1; d < 256; d <<= 1) {
        int v = (t >= d) ? s[t - d] : 0;
        __syncthreads();
        s[t] += v;
        __syncthreads();
    }
    int run = s[t] - sum;
    for (int j = 0; j < C; ++j) {
        int idx = t * C + j;
        if (idx < NB) bbase[idx] = run;
        run += vals[j];
    }
}

// Same edge ranges as k_bucket_count; LDS cursors = b*CAP + scanned base.
// Entry: {(row&255) | (col<<8), v_bits}  (col < 2^18, fits 26 bits).
__global__ __launch_bounds__(256) void k_bucket_scatter(
        const int* __restrict__ eu, const int* __restrict__ ei,
        const float* __restrict__ ev, const int* __restrict__ bh,
        int2* __restrict__ gb, int U, int E, int NB, int CH, int CAP) {
    __shared__ int lbase[NBA];
    int k = blockIdx.x;
    int t = threadIdx.x;
    for (int b = t; b < NB; b += 256) lbase[b] = b * CAP + bh[k * NBA + b];
    __syncthreads();
    int lo = k * CH, hi = min(E, lo + CH);
    for (int i = lo + t; i < hi; i += 256) {
        int u  = eu[i];
        int it = ei[i] + U;
        int vb = __float_as_int(ev[i]);
        int b1 = u >> 8;
        int p1 = atomicAdd(&lbase[b1], 1);
        if (p1 < (b1 + 1) * CAP) gb[p1] = make_int2((u & 255) | (it << 8), vb);
        int b2 = it >> 8;
        int p2 = atomicAdd(&lbase[b2], 1);
        if (p2 < (b2 + 1) * CAP) gb[p2] = make_int2((it & 255) | (u << 8), vb);
    }
}

// One block per bucket: hist + float-deg accumulate in LDS, LDS scan,
// write offs/cnt/dinv/dsq (k_dinv fused), then bucket-local CSR scatter.
__global__ __launch_bounds__(256) void k_bucket_csr(
        const int2* __restrict__ gb, const int* __restrict__ total,
        const int* __restrict__ bbase,
        int* __restrict__ offs, int* __restrict__ cnt,
        float* __restrict__ dinv, float* __restrict__ dsq,
        int2* __restrict__ csr, int N, int CAP) {
    __shared__ int   hist[256];
    __shared__ float degf[256];
    __shared__ int   offl[256];
    __shared__ int   scan[256];
    int b = blockIdx.x;
    int t = threadIdx.x;
    int n0 = b << 8;
    int nbc = min(256, N - n0);
    int cb = min(total[b], CAP);
    int base = bbase[b];
    const int2* gbb = gb + (size_t)b * CAP;

    hist[t] = 0;
    degf[t] = 0.f;
    __syncthreads();
    for (int i = t; i < cb; i += 256) {
        int2 e = gbb[i];
        int rl = e.x & 255;
        atomicAdd(&hist[rl], 1);
        atomicAdd(&degf[rl], __int_as_float(e.y));
    }
    __syncthreads();
    int h = hist[t];
    scan[t] = h;
    __syncthreads();
    for (int d = 1; d < 256; d <<= 1) {
        int v = (t >= d) ? scan[t - d] : 0;
        __syncthreads();
        scan[t] += v;
        __syncthreads();
    }
    offl[t] = scan[t] - h;           // exclusive within-bucket node offset
    if (t < nbc) {
        int node = n0 + t;
        offs[node] = base + (scan[t] - h);
        cnt[node]  = h;
        float s = degf[t];
        bool pos = (s > 0.0f);
        dinv[node] = pos ? rsqrtf(fmaxf(s, 1e-12f)) : 0.0f;
        dsq[node]  = pos ? sqrtf(s) : 0.0f;
    }
    hist[t] = 0;                     // reuse as per-node cursor
    __syncthreads();
    for (int i = t; i < cb; i += 256) {
        int2 e = gbb[i];
        int rl = e.x & 255;
        int col = (int)(((unsigned)e.x) >> 8);
        int tk = atomicAdd(&hist[rl], 1);
        csr[base + offl[rl] + tk] = make_int2(col, e.y);
    }
}

// g0 = bf16(dinv * concat(emb)). 4 elems/thread.
__global__ void k_init(const float4* __restrict__ emb_u, const float4* __restrict__ emb_i,
                       const float* __restrict__ dinv,
                       ushort4* __restrict__ g0, int U16, int N16) {
    int i = blockIdx.x * blockDim.x + threadIdx.x;
    if (i >= N16) return;
    float4 v = (i < U16) ? emb_u[i] : emb_i[i - U16];
    float d = dinv[i >> 4];
    ushort4 o;
    o.x = f32_to_bf16(v.x * d);
    o.y = f32_to_bf16(v.y * d);
    o.z = f32_to_bf16(v.z * d);
    o.w = f32_to_bf16(v.w * d);
    g0[i] = o;
}

// One wave per row. nb = lane>>4 (neighbor subgroup), q = lane&15 (dim quad).
__global__ __launch_bounds__(256) void k_layer(
        const ushort4* __restrict__ gin, ushort4* __restrict__ gout,
        const float* __restrict__ dinv,
        const int* __restrict__ offs, const int* __restrict__ cnt,
        const int2* __restrict__ csr, int N) {
    int gtid = blockIdx.x * blockDim.x + threadIdx.x;
    int row = gtid >> 6;
    int lane = threadIdx.x & 63;
    if (row >= N) return;
    int nb = lane >> 4;
    int q  = lane & 15;
    int base = offs[row];
    int c = cnt[row];

    float ax = 0.f, ay = 0.f, az = 0.f, aw = 0.f;

    for (int k0 = 0; k0 < c; k0 += 64) {
        int idx = k0 + lane;
        int2 cw = make_int2(0, 0);
        if (idx < c) cw = csr[base + idx];   // lanes >= m hold {0, 0.0f}
        int m = min(c - k0, 64);
        int j = 0;
        for (; j + 8 <= m; j += 8) {
            int   colA = __shfl(cw.x, j + nb);
            float wA   = __int_as_float(__shfl(cw.y, j + nb));
            int   colB = __shfl(cw.x, j + 4 + nb);
            float wB   = __int_as_float(__shfl(cw.y, j + 4 + nb));
            ushort4 gA = gin[(size_t)colA * 16 + q];
            ushort4 gB = gin[(size_t)colB * 16 + q];
            ax += wA * bf16_to_f32(gA.x);
            ay += wA * bf16_to_f32(gA.y);
            az += wA * bf16_to_f32(gA.z);
            aw += wA * bf16_to_f32(gA.w);
            ax += wB * bf16_to_f32(gB.x);
            ay += wB * bf16_to_f32(gB.y);
            az += wB * bf16_to_f32(gB.z);
            aw += wB * bf16_to_f32(gB.w);
        }
        for (; j < m; j += 4) {
            int   col = __shfl(cw.x, j + nb);
            float w   = __int_as_float(__shfl(cw.y, j + nb));
            ushort4 gv = gin[(size_t)col * 16 + q];
            ax += w * bf16_to_f32(gv.x);
            ay += w * bf16_to_f32(gv.y);
            az += w * bf16_to_f32(gv.z);
            aw += w * bf16_to_f32(gv.w);
        }
    }

    ax += __shfl_xor(ax, 16); ay += __shfl_xor(ay, 16);
    az += __shfl_xor(az, 16); aw += __shfl_xor(aw, 16);
    ax += __shfl_xor(ax, 32); ay += __shfl_xor(ay, 32);
    az += __shfl_xor(az, 32); aw += __shfl_xor(aw, 32);

    if (nb == 0) {
        float dr = dinv[row];
        float d2 = dr * dr;
        ushort4 o;
        o.x = f32_to_bf16(d2 * ax);
        o.y = f32_to_bf16(d2 * ay);
        o.z = f32_to_bf16(d2 * az);
        o.w = f32_to_bf16(d2 * aw);
        gout[(size_t)row * 16 + q] = o;
    }
}

// out (float4 units): [Uf | Upass | If | Ipass]; Uf/If = (e0 + sum dsq*g_l)/25.
__global__ void k_final(const float4* __restrict__ emb_u, const float4* __restrict__ emb_i,
                        const ushort4* __restrict__ g1, const ushort4* __restrict__ g2,
                        const ushort4* __restrict__ g3, const ushort4* __restrict__ g4,
                        const float* __restrict__ dsq,
                        float4* __restrict__ out, int U16, int I16) {
    int i = blockIdx.x * blockDim.x + threadIdx.x;
    int total = 2 * U16 + 2 * I16;
    if (i >= total) return;
    const float s = 1.0f / 25.0f;
    float4 r;
    if (i < U16 || (i >= 2 * U16 && i < 2 * U16 + I16)) {
        int gi, node;
        float4 e0;
        if (i < U16) { gi = i; node = i >> 4; e0 = emb_u[i]; }
        else { int j = i - 2 * U16; gi = U16 + j; node = (U16 >> 4) + (j >> 4); e0 = emb_i[j]; }
        float d = dsq[node];
        ushort4 a = g1[gi], b = g2[gi], cc = g3[gi], dd = g4[gi];
        float gx = bf16_to_f32(a.x) + bf16_to_f32(b.x) + bf16_to_f32(cc.x) + bf16_to_f32(dd.x);
        float gy = bf16_to_f32(a.y) + bf16_to_f32(b.y) + bf16_to_f32(cc.y) + bf16_to_f32(dd.y);
        float gz = bf16_to_f32(a.z) + bf16_to_f32(b.z) + bf16_to_f32(cc.z) + bf16_to_f32(dd.z);
        float gw = bf16_to_f32(a.w) + bf16_to_f32(b.w) + bf16_to_f32(cc.w) + bf16_to_f32(dd.w);
        r = make_float4((e0.x + d * gx) * s, (e0.y + d * gy) * s,
                        (e0.z + d * gz) * s, (e0.w + d * gw) * s);
    } else if (i < 2 * U16) {
        r = emb_u[i - U16];
    } else {
        r = emb_i[i - 2 * U16 - I16];
    }
    out[i] = r;
}

extern "C" void kernel_launch(void* const* d_in, const int* in_sizes, int n_in,
                              void* d_out, int out_size, void* d_ws, size_t ws_size,
                              hipStream_t stream) {
    const float* emb_u = (const float*)d_in[0];
    const float* emb_i = (const float*)d_in[1];
    const int*   eu    = (const int*)d_in[2];
    const int*   ei    = (const int*)d_in[3];
    const float* ev    = (const float*)d_in[4];

    const int U = in_sizes[0] / 64;
    const int I = in_sizes[1] / 64;
    const int N = U + I;
    const int E = in_sizes[2];
    const int DE = 2 * E;

    const int NB = (N + 255) >> 8;         // 586 buckets for N = 150000 (<= NBA)
    const int CH = (E + KB - 1) / KB;      // edges per count/scatter block

    // ---- workspace carve ----
    char* base = (char*)d_ws;
    size_t off = 0;
    int*   offs  = (int*)  (base + off); off = align_up(off + (size_t)N * 4, 256);
    int*   cnt   = (int*)  (base + off); off = align_up(off + (size_t)N * 4, 256);
    float* dinv  = (float*)(base + off); off = align_up(off + (size_t)N * 4, 256);
    float* dsq   = (float*)(base + off); off = align_up(off + (size_t)N * 4, 256);
    int*   bh    = (int*)  (base + off); off = align_up(off + (size_t)NBA * KB * 4, 256);
    int*   total = (int*)  (base + off); off = align_up(off + (size_t)NBA * 4, 256);
    int*   bbase = (int*)  (base + off); off = align_up(off + (size_t)NBA * 4, 256);
    int2*  csr   = (int2*) (base + off); off = align_up(off + (size_t)DE * 8, 256);
    unsigned short* g[5];
    for (int l = 0; l < 5; ++l) {
        g[l] = (unsigned short*)(base + off);
        off = align_up(off + (size_t)N * 64 * 2, 256);
    }
    (void)ws_size;

    // Bucket staging aliases g[1..4] (dead until layer 0 writes g[1]).
    int2* gb = (int2*)g[1];
    size_t gcap = (size_t)4 * N * 128;                 // bytes available at g[1]
    int CAP = (int)(gcap / ((size_t)NB * 8));          // per-bucket entry cap
    if (CAP > 16128) CAP = 16128;                      // ~1.5x max expected bucket load

    const int B = 256;
    k_bucket_count  <<<KB, B, 0, stream>>>(eu, ei, bh, U, E, NB, CH);
    k_scan_blocks   <<<NB, B, 0, stream>>>(bh, total, NB);
    k_scan_buckets  <<<1,  B, 0, stream>>>(total, bbase, NB);
    k_bucket_scatter<<<KB, B, 0, stream>>>(eu, ei, ev, bh, gb, U, E, NB, CH, CAP);
    k_bucket_csr    <<<NB, B, 0, stream>>>(gb, total, bbase, offs, cnt, dinv, dsq, csr, N, CAP);

    const int U16 = U * 16, I16 = I * 16, N16 = N * 16;
    k_init<<<(N16 + B - 1) / B, B, 0, stream>>>((const float4*)emb_u, (const float4*)emb_i,
                                                dinv, (ushort4*)g[0], U16, N16);

    for (int layer = 0; layer < 4; ++layer) {
        int threads = N * 64;
        k_layer<<<(threads + B - 1) / B, B, 0, stream>>>(
            (const ushort4*)g[layer], (ushort4*)g[layer + 1], dinv, offs, cnt, csr, N);
    }

    int totalv4 = 2 * U16 + 2 * I16;
    k_final<<<(totalv4 + B - 1) / B, B, 0, stream>>>(
        (const float4*)emb_u, (const float4*)emb_i,
        (const ushort4*)g[1], (const ushort4*)g[2], (const ushort4*)g[3], (const ushort4*)g[4],
        dsq, (float4*)d_out, U16, I16);
}

// Round 2
// 589.904 us; speedup vs baseline: 1.2973x; 1.0369x over previous
//
#include <hip/hip_runtime.h>

// LightGCN, atomic-free CSR build (bucketed counting sort) + bf16 g-form layers.
//
// Build pipeline (replaces k_count/k_offsets/k_scatter/k_dinv, no memset):
//   k_bucket_count   : 1024 blocks x disjoint edge ranges, LDS hist over
//                      586 node-buckets (256 nodes each), dump bh[k][b].
//   k_scan_blocks    : per-bucket exclusive scan over the 1024 block counts
//                      (in-place in bh) + bucket totals.
//   k_scan_buckets   : exclusive scan of bucket totals -> bucket CSR bases.
//   k_bucket_scatter : re-stream same edge ranges, LDS cursors preloaded with
//                      scanned bases, place packed {row_local|col<<8, v} 8B
//                      entries into per-bucket regions (cap CAP).
//   k_bucket_csr     : one block per bucket: LDS 256-bin hist + LDS float deg
//                      accumulation + LDS scan -> offs/cnt/dinv/dsq, then
//                      scatter final csr {col, v} (bucket-local destinations).
// Rationale: device-scope atomics write through the non-coherent per-XCD L2s
// (old k_count showed 140MB WRITE_SIZE for 4M atomics, 190us). Within-row
// entry order was already nondeterministic, so the bucket sort needs ZERO
// global atomics. Bucket staging aliases g[1..4] (dead until layer 0).
//
// g-form: g = dinv(*)e; s_r = sum v*g_c; g' = dinv_r^2 * s_r.
// k_final reconstructs acc = e0 + sum_l dsq*g_l (dsq = sqrt(deg)).
//
// k_layer (R1): 8 neighbor-subgroups x 8 lanes, uint4 (8 bf16 dims) per lane.
// Per 16 neighbors: 4 shfl + 2 independent 16B gathers (vs R0's 8 shfl +
// 4 loads) -- per-neighbor shfl/load instruction counts halved; FMA+cvt
// unchanged (irreducible). Cross-subgroup reduce: shfl_xor 8,16,32 at row end.

static inline size_t align_up(size_t x, size_t a) { return (x + a - 1) & ~(a - 1); }

#define NBA 640          // max buckets (N <= 163840); N = 150000 -> NB = 586
#define KB  1024         // edge-range blocks for count/scatter passes

__device__ inline unsigned short f32_to_bf16(float f) {
    unsigned int u = __float_as_uint(f);
    unsigned int r = (u + 0x7FFFu + ((u >> 16) & 1u)) >> 16;   // RNE
    return (unsigned short)r;
}
__device__ inline float bf16_to_f32(unsigned short h) {
    return __uint_as_float(((unsigned int)h) << 16);
}
__device__ inline float bf16_lo(unsigned int d) {
    return __uint_as_float(d << 16);
}
__device__ inline float bf16_hi(unsigned int d) {
    return __uint_as_float(d & 0xFFFF0000u);
}

// 1024 blocks, block k owns edges [k*CH, min(E,(k+1)*CH)).
// LDS histogram over node-buckets (node>>8); dump bh[k*NBA + b] (coalesced).
__global__ __launch_bounds__(256) void k_bucket_count(
        const int* __restrict__ eu, const int* __restrict__ ei,
        int* __restrict__ bh, int U, int E, int NB, int CH) {
    __shared__ int hist[NBA];
    int k = blockIdx.x;
    int t = threadIdx.x;
    for (int b = t; b < NBA; b += 256) hist[b] = 0;
    __syncthreads();
    int lo = k * CH, hi = min(E, lo + CH);
    for (int i = lo + t; i < hi; i += 256) {
        int u  = eu[i];
        int it = ei[i] + U;
        atomicAdd(&hist[u >> 8], 1);
        atomicAdd(&hist[it >> 8], 1);
    }
    __syncthreads();
    for (int b = t; b < NB; b += 256) bh[k * NBA + b] = hist[b];
}

// One block per bucket b: exclusive scan (in place) of bh[k][b] over k=0..1023,
// total[b] = sum. 256 threads x 4 sequential elements each.
__global__ __launch_bounds__(256) void k_scan_blocks(
        int* __restrict__ bh, int* __restrict__ total, int NB) {
    __shared__ int s[256];
    int b = blockIdx.x;
    int t = threadIdx.x;
    int k0 = t * 4;
    int vals[4];
    int sum = 0;
    #pragma unroll
    for (int j = 0; j < 4; ++j) { vals[j] = bh[(k0 + j) * NBA + b]; sum += vals[j]; }
    s[t] = sum;
    __syncthreads();
    for (int d = 1; d < 256; d <<= 1) {
        int v = (t >= d) ? s[t - d] : 0;
        __syncthreads();
        s[t] += v;
        __syncthreads();
    }
    int run = s[t] - sum;            // exclusive base for this thread's chunk
    #pragma unroll
    for (int j = 0; j < 4; ++j) { int v = vals[j]; bh[(k0 + j) * NBA + b] = run; run += v; }
    if (t == 255) total[b] = run;
}

// Single block: exclusive scan of bucket totals -> bucket CSR/entry bases.
__global__ __launch_bounds__(256) void k_scan_buckets(
        const int* __restrict__ total, int* __restrict__ bbase, int NB) {
    __shared__ int s[256];
    int t = threadIdx.x;
    int C = (NB + 255) / 256;        // <= 3 for NB <= 640 (vals[4] headroom)
    int vals[4];
    int sum = 0;
    for (int j = 0; j < C; ++j) {
        int idx = t * C + j;
        int v = (idx < NB) ? total[idx] : 0;
        vals[j] = v; sum += v;
    }
    s[t] = sum;
    __syncthreads();
    for (int d = 1; d < 256; d <<= 1) {
        int v = (t >= d) ? s[t - d] : 0;
        __syncthreads();
        s[t] += v;
        __syncthreads();
    }
    int run = s[t] - sum;
    for (int j = 0; j < C; ++j) {
        int idx = t * C + j;
        if (idx < NB) bbase[idx] = run;
        run += vals[j];
    }
}

// Same edge ranges as k_bucket_count; LDS cursors = b*CAP + scanned base.
// Entry: {(row&255) | (col<<8), v_bits}  (col < 2^18, fits 26 bits).
__global__ __launch_bounds__(256) void k_bucket_scatter(
        const int* __restrict__ eu, const int* __restrict__ ei,
        const float* __restrict__ ev, const int* __restrict__ bh,
        int2* __restrict__ gb, int U, int E, int NB, int CH, int CAP) {
    __shared__ int lbase[NBA];
    int k = blockIdx.x;
    int t = threadIdx.x;
    for (int b = t; b < NB; b += 256) lbase[b] = b * CAP + bh[k * NBA + b];
    __syncthreads();
    int lo = k * CH, hi = min(E, lo + CH);
    for (int i = lo + t; i < hi; i += 256) {
        int u  = eu[i];
        int it = ei[i] + U;
        int vb = __float_as_int(ev[i]);
        int b1 = u >> 8;
        int p1 = atomicAdd(&lbase[b1], 1);
        if (p1 < (b1 + 1) * CAP) gb[p1] = make_int2((u & 255) | (it << 8), vb);
        int b2 = it >> 8;
        int p2 = atomicAdd(&lbase[b2], 1);
        if (p2 < (b2 + 1) * CAP) gb[p2] = make_int2((it & 255) | (u << 8), vb);
    }
}

// One block per bucket: hist + float-deg accumulate in LDS, LDS scan,
// write offs/cnt/dinv/dsq (k_dinv fused), then bucket-local CSR scatter.
__global__ __launch_bounds__(256) void k_bucket_csr(
        const int2* __restrict__ gb, const int* __restrict__ total,
        const int* __restrict__ bbase,
        int* __restrict__ offs, int* __restrict__ cnt,
        float* __restrict__ dinv, float* __restrict__ dsq,
        int2* __restrict__ csr, int N, int CAP) {
    __shared__ int   hist[256];
    __shared__ float degf[256];
    __shared__ int   offl[256];
    __shared__ int   scan[256];
    int b = blockIdx.x;
    int t = threadIdx.x;
    int n0 = b << 8;
    int nbc = min(256, N - n0);
    int cb = min(total[b], CAP);
    int base = bbase[b];
    const int2* gbb = gb + (size_t)b * CAP;

    hist[t] = 0;
    degf[t] = 0.f;
    __syncthreads();
    for (int i = t; i < cb; i += 256) {
        int2 e = gbb[i];
        int rl = e.x & 255;
        atomicAdd(&hist[rl], 1);
        atomicAdd(&degf[rl], __int_as_float(e.y));
    }
    __syncthreads();
    int h = hist[t];
    scan[t] = h;
    __syncthreads();
    for (int d = 1; d < 256; d <<= 1) {
        int v = (t >= d) ? scan[t - d] : 0;
        __syncthreads();
        scan[t] += v;
        __syncthreads();
    }
    offl[t] = scan[t] - h;           // exclusive within-bucket node offset
    if (t < nbc) {
        int node = n0 + t;
        offs[node] = base + (scan[t] - h);
        cnt[node]  = h;
        float s = degf[t];
        bool pos = (s > 0.0f);
        dinv[node] = pos ? rsqrtf(fmaxf(s, 1e-12f)) : 0.0f;
        dsq[node]  = pos ? sqrtf(s) : 0.0f;
    }
    hist[t] = 0;                     // reuse as per-node cursor
    __syncthreads();
    for (int i = t; i < cb; i += 256) {
        int2 e = gbb[i];
        int rl = e.x & 255;
        int col = (int)(((unsigned)e.x) >> 8);
        int tk = atomicAdd(&hist[rl], 1);
        csr[base + offl[rl] + tk] = make_int2(col, e.y);
    }
}

// g0 = bf16(dinv * concat(emb)). 4 elems/thread.
__global__ void k_init(const float4* __restrict__ emb_u, const float4* __restrict__ emb_i,
                       const float* __restrict__ dinv,
                       ushort4* __restrict__ g0, int U16, int N16) {
    int i = blockIdx.x * blockDim.x + threadIdx.x;
    if (i >= N16) return;
    float4 v = (i < U16) ? emb_u[i] : emb_i[i - U16];
    float d = dinv[i >> 4];
    ushort4 o;
    o.x = f32_to_bf16(v.x * d);
    o.y = f32_to_bf16(v.y * d);
    o.z = f32_to_bf16(v.z * d);
    o.w = f32_to_bf16(v.w * d);
    g0[i] = o;
}

// One wave per row. nb = lane>>3 (neighbor subgroup 0..7), q = lane&7
// (dim octet: uint4 = 8 bf16 dims). Per 16 neighbors: 4 shfl + 2 independent
// 16B gathers. Padded lanes (idx>=c) hold cw={0,0} -> col 0, w 0.0 -> no-op.
__global__ __launch_bounds__(256) void k_layer(
        const uint4* __restrict__ gin, uint4* __restrict__ gout,
        const float* __restrict__ dinv,
        const int* __restrict__ offs, const int* __restrict__ cnt,
        const int2* __restrict__ csr, int N) {
    int gtid = blockIdx.x * blockDim.x + threadIdx.x;
    int row = gtid >> 6;
    int lane = threadIdx.x & 63;
    if (row >= N) return;
    int nb = lane >> 3;      // neighbor subgroup 0..7
    int q  = lane & 7;       // dim octet
    int base = offs[row];
    int c = cnt[row];

    float a0 = 0.f, a1 = 0.f, a2 = 0.f, a3 = 0.f;
    float a4 = 0.f, a5 = 0.f, a6 = 0.f, a7 = 0.f;

    for (int k0 = 0; k0 < c; k0 += 64) {
        int idx = k0 + lane;
        int2 cw = make_int2(0, 0);
        if (idx < c) cw = csr[base + idx];   // lanes >= m hold {0, 0.0f}
        int m = min(c - k0, 64);
        int j = 0;
        // 16 neighbors (2 subgroup-steps) per iteration; independent loads.
        for (; j + 16 <= m; j += 16) {
            int   colA = __shfl(cw.x, j + nb);
            float wA   = __int_as_float(__shfl(cw.y, j + nb));
            int   colB = __shfl(cw.x, j + 8 + nb);
            float wB   = __int_as_float(__shfl(cw.y, j + 8 + nb));
            uint4 gA = gin[(size_t)colA * 8 + q];
            uint4 gB = gin[(size_t)colB * 8 + q];
            a0 += wA * bf16_lo(gA.x); a1 += wA * bf16_hi(gA.x);
            a2 += wA * bf16_lo(gA.y); a3 += wA * bf16_hi(gA.y);
            a4 += wA * bf16_lo(gA.z); a5 += wA * bf16_hi(gA.z);
            a6 += wA * bf16_lo(gA.w); a7 += wA * bf16_hi(gA.w);
            a0 += wB * bf16_lo(gB.x); a1 += wB * bf16_hi(gB.x);
            a2 += wB * bf16_lo(gB.y); a3 += wB * bf16_hi(gB.y);
            a4 += wB * bf16_lo(gB.z); a5 += wB * bf16_hi(gB.z);
            a6 += wB * bf16_lo(gB.w); a7 += wB * bf16_hi(gB.w);
        }
        for (; j < m; j += 8) {
            // tail: lanes with j+nb >= m read cw=(0,0) from padded lanes
            // (j+nb <= 63 always: last j = 8*floor((m-1)/8) <= 56, nb <= 7)
            int   col = __shfl(cw.x, j + nb);
            float w   = __int_as_float(__shfl(cw.y, j + nb));
            uint4 gv = gin[(size_t)col * 8 + q];
            a0 += w * bf16_lo(gv.x); a1 += w * bf16_hi(gv.x);
            a2 += w * bf16_lo(gv.y); a3 += w * bf16_hi(gv.y);
            a4 += w * bf16_lo(gv.z); a5 += w * bf16_hi(gv.z);
            a6 += w * bf16_lo(gv.w); a7 += w * bf16_hi(gv.w);
        }
    }

    // reduce across the 8 neighbor subgroups (lanes xor 8, 16, 32)
    #pragma unroll
    for (int mask = 8; mask <= 32; mask <<= 1) {
        a0 += __shfl_xor(a0, mask); a1 += __shfl_xor(a1, mask);
        a2 += __shfl_xor(a2, mask); a3 += __shfl_xor(a3, mask);
        a4 += __shfl_xor(a4, mask); a5 += __shfl_xor(a5, mask);
        a6 += __shfl_xor(a6, mask); a7 += __shfl_xor(a7, mask);
    }

    if (nb == 0) {
        float dr = dinv[row];
        float d2 = dr * dr;
        uint4 o;
        o.x = (unsigned int)f32_to_bf16(d2 * a0) | ((unsigned int)f32_to_bf16(d2 * a1) << 16);
        o.y = (unsigned int)f32_to_bf16(d2 * a2) | ((unsigned int)f32_to_bf16(d2 * a3) << 16);
        o.z = (unsigned int)f32_to_bf16(d2 * a4) | ((unsigned int)f32_to_bf16(d2 * a5) << 16);
        o.w = (unsigned int)f32_to_bf16(d2 * a6) | ((unsigned int)f32_to_bf16(d2 * a7) << 16);
        gout[(size_t)row * 8 + q] = o;
    }
}

// out (float4 units): [Uf | Upass | If | Ipass]; Uf/If = (e0 + sum dsq*g_l)/25.
__global__ void k_final(const float4* __restrict__ emb_u, const float4* __restrict__ emb_i,
                        const ushort4* __restrict__ g1, const ushort4* __restrict__ g2,
                        const ushort4* __restrict__ g3, const ushort4* __restrict__ g4,
                        const float* __restrict__ dsq,
                        float4* __restrict__ out, int U16, int I16) {
    int i = blockIdx.x * blockDim.x + threadIdx.x;
    int total = 2 * U16 + 2 * I16;
    if (i >= total) return;
    const float s = 1.0f / 25.0f;
    float4 r;
    if (i < U16 || (i >= 2 * U16 && i < 2 * U16 + I16)) {
        int gi, node;
        float4 e0;
        if (i < U16) { gi = i; node = i >> 4; e0 = emb_u[i]; }
        else { int j = i - 2 * U16; gi = U16 + j; node = (U16 >> 4) + (j >> 4); e0 = emb_i[j]; }
        float d = dsq[node];
        ushort4 a = g1[gi], b = g2[gi], cc = g3[gi], dd = g4[gi];
        float gx = bf16_to_f32(a.x) + bf16_to_f32(b.x) + bf16_to_f32(cc.x) + bf16_to_f32(dd.x);
        float gy = bf16_to_f32(a.y) + bf16_to_f32(b.y) + bf16_to_f32(cc.y) + bf16_to_f32(dd.y);
        float gz = bf16_to_f32(a.z) + bf16_to_f32(b.z) + bf16_to_f32(cc.z) + bf16_to_f32(dd.z);
        float gw = bf16_to_f32(a.w) + bf16_to_f32(b.w) + bf16_to_f32(cc.w) + bf16_to_f32(dd.w);
        r = make_float4((e0.x + d * gx) * s, (e0.y + d * gy) * s,
                        (e0.z + d * gz) * s, (e0.w + d * gw) * s);
    } else if (i < 2 * U16) {
        r = emb_u[i - U16];
    } else {
        r = emb_i[i - 2 * U16 - I16];
    }
    out[i] = r;
}

extern "C" void kernel_launch(void* const* d_in, const int* in_sizes, int n_in,
                              void* d_out, int out_size, void* d_ws, size_t ws_size,
                              hipStream_t stream) {
    const float* emb_u = (const float*)d_in[0];
    const float* emb_i = (const float*)d_in[1];
    const int*   eu    = (const int*)d_in[2];
    const int*   ei    = (const int*)d_in[3];
    const float* ev    = (const float*)d_in[4];

    const int U = in_sizes[0] / 64;
    const int I = in_sizes[1] / 64;
    const int N = U + I;
    const int E = in_sizes[2];
    const int DE = 2 * E;

    const int NB = (N + 255) >> 8;         // 586 buckets for N = 150000 (<= NBA)
    const int CH = (E + KB - 1) / KB;      // edges per count/scatter block

    // ---- workspace carve ----
    char* base = (char*)d_ws;
    size_t off = 0;
    int*   offs  = (int*)  (base + off); off = align_up(off + (size_t)N * 4, 256);
    int*   cnt   = (int*)  (base + off); off = align_up(off + (size_t)N * 4, 256);
    float* dinv  = (float*)(base + off); off = align_up(off + (size_t)N * 4, 256);
    float* dsq   = (float*)(base + off); off = align_up(off + (size_t)N * 4, 256);
    int*   bh    = (int*)  (base + off); off = align_up(off + (size_t)NBA * KB * 4, 256);
    int*   total = (int*)  (base + off); off = align_up(off + (size_t)NBA * 4, 256);
    int*   bbase = (int*)  (base + off); off = align_up(off + (size_t)NBA * 4, 256);
    int2*  csr   = (int2*) (base + off); off = align_up(off + (size_t)DE * 8, 256);
    unsigned short* g[5];
    for (int l = 0; l < 5; ++l) {
        g[l] = (unsigned short*)(base + off);
        off = align_up(off + (size_t)N * 64 * 2, 256);
    }
    (void)ws_size;

    // Bucket staging aliases g[1..4] (dead until layer 0 writes g[1]).
    int2* gb = (int2*)g[1];
    size_t gcap = (size_t)4 * N * 128;                 // bytes available at g[1]
    int CAP = (int)(gcap / ((size_t)NB * 8));          // per-bucket entry cap
    if (CAP > 16128) CAP = 16128;                      // ~1.5x max expected bucket load

    const int B = 256;
    k_bucket_count  <<<KB, B, 0, stream>>>(eu, ei, bh, U, E, NB, CH);
    k_scan_blocks   <<<NB, B, 0, stream>>>(bh, total, NB);
    k_scan_buckets  <<<1,  B, 0, stream>>>(total, bbase, NB);
    k_bucket_scatter<<<KB, B, 0, stream>>>(eu, ei, ev, bh, gb, U, E, NB, CH, CAP);
    k_bucket_csr    <<<NB, B, 0, stream>>>(gb, total, bbase, offs, cnt, dinv, dsq, csr, N, CAP);

    const int U16 = U * 16, I16 = I * 16, N16 = N * 16;
    k_init<<<(N16 + B - 1) / B, B, 0, stream>>>((const float4*)emb_u, (const float4*)emb_i,
                                                dinv, (ushort4*)g[0], U16, N16);

    for (int layer = 0; layer < 4; ++layer) {
        int threads = N * 64;
        k_layer<<<(threads + B - 1) / B, B, 0, stream>>>(
            (const uint4*)g[layer], (uint4*)g[layer + 1], dinv, offs, cnt, csr, N);
    }

    int totalv4 = 2 * U16 + 2 * I16;
    k_final<<<(totalv4 + B - 1) / B, B, 0, stream>>>(
        (const float4*)emb_u, (const float4*)emb_i,
        (const ushort4*)g[1], (const ushort4*)g[2], (const ushort4*)g[3], (const ushort4*)g[4],
        dsq, (float4*)d_out, U16, I16);
}

// Round 3
// 545.541 us; speedup vs baseline: 1.4028x; 1.0813x over previous
//
#include <hip/hip_runtime.h>

// LightGCN, atomic-free CSR build (bucketed counting sort) + bf16 g-form layers.
//
// Build pipeline (no global atomics, no memset):
//   k_bucket_count   : 1024 blocks x disjoint edge ranges, LDS hist over
//                      node-buckets (256 nodes each), dump bh[k][b].
//   k_scan_blocks    : per-bucket exclusive scan over the 1024 block counts
//                      (in-place in bh) + bucket totals.
//   k_scan_buckets   : exclusive scan of per-bucket ALLOC sizes
//                      (align4(total)+768) -> 4-entry-aligned bucket bases
//                      with worst-case per-node padding slack.
//   k_bucket_scatter : re-stream edge ranges, LDS cursors preloaded with
//                      scanned bases, place packed {row_local|col<<8, v} 8B
//                      entries into per-bucket staging regions (cap CAP).
//   k_bucket_csr     : one block per bucket: LDS 256-bin hist + float deg
//                      accumulation + LDS scan of align4(h) -> offs/cnt/
//                      dinv/dsq, zero-fill pad slots, then bucket-local
//                      CSR scatter. Rows are padded to 4-entry multiples
//                      ({col=0,w=0} no-op slots) with 32B-aligned bases.
//
// g-form: g = dinv(*)e; s_r = sum v*g_c; g' = dinv_r^2 * s_r.
// k_final reconstructs acc = e0 + sum_l dsq*g_l (dsq = sqrt(deg)).
//
// k_layer (R2): GROUP-PER-ROW. 8 lanes per row (lane q holds dims 8q..8q+7
// as uint4), 8 rows per wave. No shuffles (csr entry broadcast-loads to the
// 8-lane group), no reduction epilogue (each lane's accumulators ARE the
// result), 8x fewer waves than wave-per-row. Inner loop: 2x dwordx4 csr
// loads + 4 independent 16B row gathers per 4 neighbors, next csr block
// prefetched under the FMAs. Padded rows make the loop branch-free.

static inline size_t align_up(size_t x, size_t a) { return (x + a - 1) & ~(a - 1); }

#define NBA 640          // max buckets (N <= 163840); N = 150000 -> NB = 586
#define KB  1024         // edge-range blocks for count/scatter passes

__device__ inline unsigned short f32_to_bf16(float f) {
    unsigned int u = __float_as_uint(f);
    unsigned int r = (u + 0x7FFFu + ((u >> 16) & 1u)) >> 16;   // RNE
    return (unsigned short)r;
}
__device__ inline float bf16_to_f32(unsigned short h) {
    return __uint_as_float(((unsigned int)h) << 16);
}
__device__ inline float bf16_lo(unsigned int d) {
    return __uint_as_float(d << 16);
}
__device__ inline float bf16_hi(unsigned int d) {
    return __uint_as_float(d & 0xFFFF0000u);
}

// 1024 blocks, block k owns edges [k*CH, min(E,(k+1)*CH)).
// LDS histogram over node-buckets (node>>8); dump bh[k*NBA + b] (coalesced).
__global__ __launch_bounds__(256) void k_bucket_count(
        const int* __restrict__ eu, const int* __restrict__ ei,
        int* __restrict__ bh, int U, int E, int NB, int CH) {
    __shared__ int hist[NBA];
    int k = blockIdx.x;
    int t = threadIdx.x;
    for (int b = t; b < NBA; b += 256) hist[b] = 0;
    __syncthreads();
    int lo = k * CH, hi = min(E, lo + CH);
    for (int i = lo + t; i < hi; i += 256) {
        int u  = eu[i];
        int it = ei[i] + U;
        atomicAdd(&hist[u >> 8], 1);
        atomicAdd(&hist[it >> 8], 1);
    }
    __syncthreads();
    for (int b = t; b < NB; b += 256) bh[k * NBA + b] = hist[b];
}

// One block per bucket b: exclusive scan (in place) of bh[k][b] over k=0..1023,
// total[b] = sum. 256 threads x 4 sequential elements each.
__global__ __launch_bounds__(256) void k_scan_blocks(
        int* __restrict__ bh, int* __restrict__ total, int NB) {
    __shared__ int s[256];
    int b = blockIdx.x;
    int t = threadIdx.x;
    int k0 = t * 4;
    int vals[4];
    int sum = 0;
    #pragma unroll
    for (int j = 0; j < 4; ++j) { vals[j] = bh[(k0 + j) * NBA + b]; sum += vals[j]; }
    s[t] = sum;
    __syncthreads();
    for (int d = 1; d < 256; d <<= 1) {
        int v = (t >= d) ? s[t - d] : 0;
        __syncthreads();
        s[t] += v;
        __syncthreads();
    }
    int run = s[t] - sum;            // exclusive base for this thread's chunk
    #pragma unroll
    for (int j = 0; j < 4; ++j) { int v = vals[j]; bh[(k0 + j) * NBA + b] = run; run += v; }
    if (t == 255) total[b] = run;
}

// Single block: exclusive scan of per-bucket ALLOC sizes -> bucket CSR bases.
// alloc_b = align4(total_b) + 768 (worst-case per-node align4 padding for
// 256 nodes); all bases stay multiples of 4 entries (32B-aligned in csr).
__global__ __launch_bounds__(256) void k_scan_buckets(
        const int* __restrict__ total, int* __restrict__ bbase, int NB) {
    __shared__ int s[256];
    int t = threadIdx.x;
    int C = (NB + 255) / 256;        // <= 3 for NB <= 640 (vals[4] headroom)
    int vals[4];
    int sum = 0;
    for (int j = 0; j < C; ++j) {
        int idx = t * C + j;
        int v = (idx < NB) ? (((total[idx] + 3) & ~3) + 768) : 0;
        vals[j] = v; sum += v;
    }
    s[t] = sum;
    __syncthreads();
    for (int d = 1; d < 256; d <<= 1) {
        int v = (t >= d) ? s[t - d] : 0;
        __syncthreads();
        s[t] += v;
        __syncthreads();
    }
    int run = s[t] - sum;
    for (int j = 0; j < C; ++j) {
        int idx = t * C + j;
        if (idx < NB) bbase[idx] = run;
        run += vals[j];
    }
}

// Same edge ranges as k_bucket_count; LDS cursors = b*CAP + scanned base.
// Entry: {(row&255) | (col<<8), v_bits}  (col < 2^18, fits 26 bits).
__global__ __launch_bounds__(256) void k_bucket_scatter(
        const int* __restrict__ eu, const int* __restrict__ ei,
        const float* __restrict__ ev, const int* __restrict__ bh,
        int2* __restrict__ gb, int U, int E, int NB, int CH, int CAP) {
    __shared__ int lbase[NBA];
    int k = blockIdx.x;
    int t = threadIdx.x;
    for (int b = t; b < NB; b += 256) lbase[b] = b * CAP + bh[k * NBA + b];
    __syncthreads();
    int lo = k * CH, hi = min(E, lo + CH);
    for (int i = lo + t; i < hi; i += 256) {
        int u  = eu[i];
        int it = ei[i] + U;
        int vb = __float_as_int(ev[i]);
        int b1 = u >> 8;
        int p1 = atomicAdd(&lbase[b1], 1);
        if (p1 < (b1 + 1) * CAP) gb[p1] = make_int2((u & 255) | (it << 8), vb);
        int b2 = it >> 8;
        int p2 = atomicAdd(&lbase[b2], 1);
        if (p2 < (b2 + 1) * CAP) gb[p2] = make_int2((it & 255) | (u << 8), vb);
    }
}

// One block per bucket: hist + float-deg accumulate in LDS, LDS scan of
// padded (align4) per-node sizes, write offs/cnt/dinv/dsq, zero-fill pad
// slots, then bucket-local CSR scatter.
__global__ __launch_bounds__(256) void k_bucket_csr(
        const int2* __restrict__ gb, const int* __restrict__ total,
        const int* __restrict__ bbase,
        int* __restrict__ offs, int* __restrict__ cnt,
        float* __restrict__ dinv, float* __restrict__ dsq,
        int2* __restrict__ csr, int N, int CAP) {
    __shared__ int   hist[256];
    __shared__ float degf[256];
    __shared__ int   offl[256];
    __shared__ int   scan[256];
    int b = blockIdx.x;
    int t = threadIdx.x;
    int n0 = b << 8;
    int nbc = min(256, N - n0);
    int cb = min(total[b], CAP);
    int base = bbase[b];
    const int2* gbb = gb + (size_t)b * CAP;

    hist[t] = 0;
    degf[t] = 0.f;
    __syncthreads();
    for (int i = t; i < cb; i += 256) {
        int2 e = gbb[i];
        int rl = e.x & 255;
        atomicAdd(&hist[rl], 1);
        atomicAdd(&degf[rl], __int_as_float(e.y));
    }
    __syncthreads();
    int h = hist[t];
    int h4 = (h + 3) & ~3;           // padded per-node size
    scan[t] = h4;
    __syncthreads();
    for (int d = 1; d < 256; d <<= 1) {
        int v = (t >= d) ? scan[t - d] : 0;
        __syncthreads();
        scan[t] += v;
        __syncthreads();
    }
    int off4 = scan[t] - h4;         // exclusive padded within-bucket offset
    offl[t] = off4;
    if (t < nbc) {
        int node = n0 + t;
        offs[node] = base + off4;
        cnt[node]  = h;
        float s = degf[t];
        bool pos = (s > 0.0f);
        dinv[node] = pos ? rsqrtf(fmaxf(s, 1e-12f)) : 0.0f;
        dsq[node]  = pos ? sqrtf(s) : 0.0f;
        for (int p = h; p < h4; ++p)                 // zero-fill pad slots
            csr[base + off4 + p] = make_int2(0, 0);
    }
    hist[t] = 0;                     // reuse as per-node cursor
    __syncthreads();
    for (int i = t; i < cb; i += 256) {
        int2 e = gbb[i];
        int rl = e.x & 255;
        int col = (int)(((unsigned)e.x) >> 8);
        int tk = atomicAdd(&hist[rl], 1);
        csr[base + offl[rl] + tk] = make_int2(col, e.y);
    }
}

// g0 = bf16(dinv * concat(emb)). 4 elems/thread.
__global__ void k_init(const float4* __restrict__ emb_u, const float4* __restrict__ emb_i,
                       const float* __restrict__ dinv,
                       ushort4* __restrict__ g0, int U16, int N16) {
    int i = blockIdx.x * blockDim.x + threadIdx.x;
    if (i >= N16) return;
    float4 v = (i < U16) ? emb_u[i] : emb_i[i - U16];
    float d = dinv[i >> 4];
    ushort4 o;
    o.x = f32_to_bf16(v.x * d);
    o.y = f32_to_bf16(v.y * d);
    o.z = f32_to_bf16(v.z * d);
    o.w = f32_to_bf16(v.w * d);
    g0[i] = o;
}

// GROUP-PER-ROW: 8 lanes per row (q = lane&7 holds dims 8q..8q+7), 8 rows
// per wave. csr rows padded to 4-entry multiples, 32B-aligned -> inner loop
// is branch-free: 2x dwordx4 csr loads (broadcast within group) + 4
// independent row gathers per 4 neighbors; next csr block prefetched under
// the FMAs. Pad entries {col=0,w=0} gather row 0 and add 0 (no-op).
__global__ __launch_bounds__(256) void k_layer(
        const uint4* __restrict__ gin, uint4* __restrict__ gout,
        const float* __restrict__ dinv,
        const int* __restrict__ offs, const int* __restrict__ cnt,
        const int2* __restrict__ csr, int N) {
    int gtid = blockIdx.x * blockDim.x + threadIdx.x;
    int row = gtid >> 3;
    unsigned q = threadIdx.x & 7;
    if (row >= N) return;
    int base = offs[row];
    int c = cnt[row];
    int nIter = (c + 3) >> 2;        // 4 neighbors per iteration

    float a0 = 0.f, a1 = 0.f, a2 = 0.f, a3 = 0.f;
    float a4 = 0.f, a5 = 0.f, a6 = 0.f, a7 = 0.f;

    const uint4* ep4 = (const uint4*)(csr + base);   // 32B-aligned
    uint4 E0 = make_uint4(0, 0, 0, 0), E1 = E0;
    if (nIter > 0) { E0 = ep4[0]; E1 = ep4[1]; }     // {c0,w0,c1,w1},{c2,w2,c3,w3}

    for (int i = 0; i < nIter; ++i) {
        uint4 G0 = gin[(E0.x << 3) | q];
        uint4 G1 = gin[(E0.z << 3) | q];
        uint4 G2 = gin[(E1.x << 3) | q];
        uint4 G3 = gin[(E1.z << 3) | q];
        // prefetch next csr block (reads <=32B past row end; slack allocated)
        uint4 P0 = ep4[2 * i + 2];
        uint4 P1 = ep4[2 * i + 3];
        float w0 = __uint_as_float(E0.y);
        float w1 = __uint_as_float(E0.w);
        float w2 = __uint_as_float(E1.y);
        float w3 = __uint_as_float(E1.w);
        a0 += w0 * bf16_lo(G0.x); a1 += w0 * bf16_hi(G0.x);
        a2 += w0 * bf16_lo(G0.y); a3 += w0 * bf16_hi(G0.y);
        a4 += w0 * bf16_lo(G0.z); a5 += w0 * bf16_hi(G0.z);
        a6 += w0 * bf16_lo(G0.w); a7 += w0 * bf16_hi(G0.w);
        a0 += w1 * bf16_lo(G1.x); a1 += w1 * bf16_hi(G1.x);
        a2 += w1 * bf16_lo(G1.y); a3 += w1 * bf16_hi(G1.y);
        a4 += w1 * bf16_lo(G1.z); a5 += w1 * bf16_hi(G1.z);
        a6 += w1 * bf16_lo(G1.w); a7 += w1 * bf16_hi(G1.w);
        a0 += w2 * bf16_lo(G2.x); a1 += w2 * bf16_hi(G2.x);
        a2 += w2 * bf16_lo(G2.y); a3 += w2 * bf16_hi(G2.y);
        a4 += w2 * bf16_lo(G2.z); a5 += w2 * bf16_hi(G2.z);
        a6 += w2 * bf16_lo(G2.w); a7 += w2 * bf16_hi(G2.w);
        a0 += w3 * bf16_lo(G3.x); a1 += w3 * bf16_hi(G3.x);
        a2 += w3 * bf16_lo(G3.y); a3 += w3 * bf16_hi(G3.y);
        a4 += w3 * bf16_lo(G3.z); a5 += w3 * bf16_hi(G3.z);
        a6 += w3 * bf16_lo(G3.w); a7 += w3 * bf16_hi(G3.w);
        E0 = P0; E1 = P1;
    }

    float dr = dinv[row];
    float d2 = dr * dr;
    uint4 o;
    o.x = (unsigned int)f32_to_bf16(d2 * a0) | ((unsigned int)f32_to_bf16(d2 * a1) << 16);
    o.y = (unsigned int)f32_to_bf16(d2 * a2) | ((unsigned int)f32_to_bf16(d2 * a3) << 16);
    o.z = (unsigned int)f32_to_bf16(d2 * a4) | ((unsigned int)f32_to_bf16(d2 * a5) << 16);
    o.w = (unsigned int)f32_to_bf16(d2 * a6) | ((unsigned int)f32_to_bf16(d2 * a7) << 16);
    gout[((unsigned)row << 3) | q] = o;
}

// out (float4 units): [Uf | Upass | If | Ipass]; Uf/If = (e0 + sum dsq*g_l)/25.
__global__ void k_final(const float4* __restrict__ emb_u, const float4* __restrict__ emb_i,
                        const ushort4* __restrict__ g1, const ushort4* __restrict__ g2,
                        const ushort4* __restrict__ g3, const ushort4* __restrict__ g4,
                        const float* __restrict__ dsq,
                        float4* __restrict__ out, int U16, int I16) {
    int i = blockIdx.x * blockDim.x + threadIdx.x;
    int total = 2 * U16 + 2 * I16;
    if (i >= total) return;
    const float s = 1.0f / 25.0f;
    float4 r;
    if (i < U16 || (i >= 2 * U16 && i < 2 * U16 + I16)) {
        int gi, node;
        float4 e0;
        if (i < U16) { gi = i; node = i >> 4; e0 = emb_u[i]; }
        else { int j = i - 2 * U16; gi = U16 + j; node = (U16 >> 4) + (j >> 4); e0 = emb_i[j]; }
        float d = dsq[node];
        ushort4 a = g1[gi], b = g2[gi], cc = g3[gi], dd = g4[gi];
        float gx = bf16_to_f32(a.x) + bf16_to_f32(b.x) + bf16_to_f32(cc.x) + bf16_to_f32(dd.x);
        float gy = bf16_to_f32(a.y) + bf16_to_f32(b.y) + bf16_to_f32(cc.y) + bf16_to_f32(dd.y);
        float gz = bf16_to_f32(a.z) + bf16_to_f32(b.z) + bf16_to_f32(cc.z) + bf16_to_f32(dd.z);
        float gw = bf16_to_f32(a.w) + bf16_to_f32(b.w) + bf16_to_f32(cc.w) + bf16_to_f32(dd.w);
        r = make_float4((e0.x + d * gx) * s, (e0.y + d * gy) * s,
                        (e0.z + d * gz) * s, (e0.w + d * gw) * s);
    } else if (i < 2 * U16) {
        r = emb_u[i - U16];
    } else {
        r = emb_i[i - 2 * U16 - I16];
    }
    out[i] = r;
}

extern "C" void kernel_launch(void* const* d_in, const int* in_sizes, int n_in,
                              void* d_out, int out_size, void* d_ws, size_t ws_size,
                              hipStream_t stream) {
    const float* emb_u = (const float*)d_in[0];
    const float* emb_i = (const float*)d_in[1];
    const int*   eu    = (const int*)d_in[2];
    const int*   ei    = (const int*)d_in[3];
    const float* ev    = (const float*)d_in[4];

    const int U = in_sizes[0] / 64;
    const int I = in_sizes[1] / 64;
    const int N = U + I;
    const int E = in_sizes[2];
    const int DE = 2 * E;

    const int NB = (N + 255) >> 8;         // 586 buckets for N = 150000 (<= NBA)
    const int CH = (E + KB - 1) / KB;      // edges per count/scatter block

    // ---- workspace carve ----
    char* base = (char*)d_ws;
    size_t off = 0;
    int*   offs  = (int*)  (base + off); off = align_up(off + (size_t)N * 4, 256);
    int*   cnt   = (int*)  (base + off); off = align_up(off + (size_t)N * 4, 256);
    float* dinv  = (float*)(base + off); off = align_up(off + (size_t)N * 4, 256);
    float* dsq   = (float*)(base + off); off = align_up(off + (size_t)N * 4, 256);
    int*   bh    = (int*)  (base + off); off = align_up(off + (size_t)NBA * KB * 4, 256);
    int*   total = (int*)  (base + off); off = align_up(off + (size_t)NBA * 4, 256);
    int*   bbase = (int*)  (base + off); off = align_up(off + (size_t)NBA * 4, 256);
    // padded CSR: DE entries + per-bucket (align4 + 768) slack + prefetch slack
    int2*  csr   = (int2*) (base + off);
    off = align_up(off + ((size_t)DE + (size_t)NBA * 772 + 16) * 8, 256);
    unsigned short* g[5];
    for (int l = 0; l < 5; ++l) {
        g[l] = (unsigned short*)(base + off);
        off = align_up(off + (size_t)N * 64 * 2, 256);
    }
    (void)ws_size;

    // Bucket staging aliases g[1..4] (dead until layer 0 writes g[1]).
    int2* gb = (int2*)g[1];
    size_t gcap = (size_t)4 * N * 128;                 // bytes available at g[1]
    int CAP = (int)(gcap / ((size_t)NB * 8));          // per-bucket entry cap
    if (CAP > 16128) CAP = 16128;                      // ~1.5x max expected bucket load

    const int B = 256;
    k_bucket_count  <<<KB, B, 0, stream>>>(eu, ei, bh, U, E, NB, CH);
    k_scan_blocks   <<<NB, B, 0, stream>>>(bh, total, NB);
    k_scan_buckets  <<<1,  B, 0, stream>>>(total, bbase, NB);
    k_bucket_scatter<<<KB, B, 0, stream>>>(eu, ei, ev, bh, gb, U, E, NB, CH, CAP);
    k_bucket_csr    <<<NB, B, 0, stream>>>(gb, total, bbase, offs, cnt, dinv, dsq, csr, N, CAP);

    const int U16 = U * 16, I16 = I * 16, N16 = N * 16;
    k_init<<<(N16 + B - 1) / B, B, 0, stream>>>((const float4*)emb_u, (const float4*)emb_i,
                                                dinv, (ushort4*)g[0], U16, N16);

    for (int layer = 0; layer < 4; ++layer) {
        int threads = N * 8;               // 8 lanes per row
        k_layer<<<(threads + B - 1) / B, B, 0, stream>>>(
            (const uint4*)g[layer], (uint4*)g[layer + 1], dinv, offs, cnt, csr, N);
    }

    int totalv4 = 2 * U16 + 2 * I16;
    k_final<<<(totalv4 + B - 1) / B, B, 0, stream>>>(
        (const float4*)emb_u, (const float4*)emb_i,
        (const ushort4*)g[1], (const ushort4*)g[2], (const ushort4*)g[3], (const ushort4*)g[4],
        dsq, (float4*)d_out, U16, I16);
}

// Round 4
// 543.039 us; speedup vs baseline: 1.4093x; 1.0046x over previous
//
#include <hip/hip_runtime.h>

// LightGCN, atomic-free CSR build (bucketed counting sort) + bf16 g-form layers.
//
// Build pipeline (no global atomics, no memset):
//   k_bucket_count   : 1024 blocks x disjoint edge ranges, LDS hist over
//                      node-buckets (1024 nodes each), dump bh[k][b].
//   k_scan_blocks    : per-bucket exclusive scan over the 1024 block counts
//                      (in-place in bh) + bucket totals.
//   k_scan_buckets   : exclusive scan of per-bucket ALLOC sizes
//                      (align4(total)+3072) -> 4-entry-aligned bucket bases
//                      with worst-case per-node padding slack.
//   k_bucket_scatter : re-stream edge ranges; SORT the block's entries by
//                      bucket in LDS (hist -> scan -> place w/ precomputed
//                      global dst), then stream out. Consecutive threads
//                      write consecutive slots of a bucket segment (~27
//                      entries avg) -> near-full-line transactions. (R2's
//                      unsorted version showed 101MB WRITE_SIZE for 32MB
//                      logical: random 8B writes can't merge in L2.)
//   k_bucket_csr     : one 1024-thread block per bucket: LDS 1024-bin hist +
//                      float deg accumulation + LDS scan of align4(h) ->
//                      offs/cnt/dinv/dsq, zero-fill pad slots, then
//                      bucket-local CSR scatter. Rows padded to 4-entry
//                      multiples ({col=0,w=0} no-op slots), 32B-aligned.
//
// g-form: g = dinv(*)e; s_r = sum v*g_c; g' = dinv_r^2 * s_r.
// k_final reconstructs acc = e0 + sum_l dsq*g_l (dsq = sqrt(deg)).
//
// k_layer (R2): GROUP-PER-ROW. 8 lanes per row (lane q holds dims 8q..8q+7
// as uint4), 8 rows per wave. No shuffles, no reduction epilogue. Inner
// loop: 2x dwordx4 csr loads + 4 independent 16B row gathers per 4
// neighbors, next csr block prefetched under the FMAs. Branch-free.

static inline size_t align_up(size_t x, size_t a) { return (x + a - 1) & ~(a - 1); }

#define BS_LOG 10        // bucket = 1024 nodes
#define NBA 160          // max buckets (N <= 163840); N = 150000 -> NB = 147
#define KB  1024         // edge-range blocks for count/scatter passes
#define ENT 4096         // staged entries per scatter block (2*CH <= 3908)

__device__ inline unsigned short f32_to_bf16(float f) {
    unsigned int u = __float_as_uint(f);
    unsigned int r = (u + 0x7FFFu + ((u >> 16) & 1u)) >> 16;   // RNE
    return (unsigned short)r;
}
__device__ inline float bf16_to_f32(unsigned short h) {
    return __uint_as_float(((unsigned int)h) << 16);
}
__device__ inline float bf16_lo(unsigned int d) {
    return __uint_as_float(d << 16);
}
__device__ inline float bf16_hi(unsigned int d) {
    return __uint_as_float(d & 0xFFFF0000u);
}

// 1024 blocks, block k owns edges [k*CH, min(E,(k+1)*CH)).
// LDS histogram over node-buckets (node>>10); dump bh[k*NBA + b] (coalesced).
__global__ __launch_bounds__(256) void k_bucket_count(
        const int* __restrict__ eu, const int* __restrict__ ei,
        int* __restrict__ bh, int U, int E, int NB, int CH) {
    __shared__ int hist[NBA];
    int k = blockIdx.x;
    int t = threadIdx.x;
    if (t < NBA) hist[t] = 0;
    __syncthreads();
    int lo = k * CH, hi = min(E, lo + CH);
    for (int i = lo + t; i < hi; i += 256) {
        int u  = eu[i];
        int it = ei[i] + U;
        atomicAdd(&hist[u >> BS_LOG], 1);
        atomicAdd(&hist[it >> BS_LOG], 1);
    }
    __syncthreads();
    if (t < NB) bh[k * NBA + t] = hist[t];
}

// One block per bucket b: exclusive scan (in place) of bh[k][b] over k=0..1023,
// total[b] = sum. 256 threads x 4 sequential elements each.
__global__ __launch_bounds__(256) void k_scan_blocks(
        int* __restrict__ bh, int* __restrict__ total, int NB) {
    __shared__ int s[256];
    int b = blockIdx.x;
    int t = threadIdx.x;
    int k0 = t * 4;
    int vals[4];
    int sum = 0;
    #pragma unroll
    for (int j = 0; j < 4; ++j) { vals[j] = bh[(k0 + j) * NBA + b]; sum += vals[j]; }
    s[t] = sum;
    __syncthreads();
    for (int d = 1; d < 256; d <<= 1) {
        int v = (t >= d) ? s[t - d] : 0;
        __syncthreads();
        s[t] += v;
        __syncthreads();
    }
    int run = s[t] - sum;            // exclusive base for this thread's chunk
    #pragma unroll
    for (int j = 0; j < 4; ++j) { int v = vals[j]; bh[(k0 + j) * NBA + b] = run; run += v; }
    if (t == 255) total[b] = run;
}

// Single block: exclusive scan of per-bucket ALLOC sizes -> bucket CSR bases.
// alloc_b = align4(total_b) + 3072 (worst-case per-node align4 padding for
// 1024 nodes); all bases stay multiples of 4 entries (32B-aligned in csr).
__global__ __launch_bounds__(256) void k_scan_buckets(
        const int* __restrict__ total, int* __restrict__ bbase, int NB) {
    __shared__ int s[256];
    int t = threadIdx.x;
    int v = (t < NB) ? (((total[t] + 3) & ~3) + 3072) : 0;
    s[t] = v;
    __syncthreads();
    for (int d = 1; d < 256; d <<= 1) {
        int x = (t >= d) ? s[t - d] : 0;
        __syncthreads();
        s[t] += x;
        __syncthreads();
    }
    if (t < NB) bbase[t] = s[t] - v;
}

// LDS-sorted scatter. Entry: {(node&1023) | (col<<10), v_bits} (28 bits).
// Phase 1: local hist. Phase 2: scan -> segment starts + global-dst deltas.
// Phase 3: place entry + dst into LDS. Phase 4: stream out (consecutive
// threads -> consecutive slots of the same bucket segment -> coalesced).
__global__ __launch_bounds__(256) void k_bucket_scatter(
        const int* __restrict__ eu, const int* __restrict__ ei,
        const float* __restrict__ ev, const int* __restrict__ bh,
        int2* __restrict__ gb, int U, int E, int NB, int CH, int CAP) {
    __shared__ uint2 sent[ENT];
    __shared__ int   sdst[ENT];
    __shared__ int   lcur[NBA];
    __shared__ int   ldif[NBA];
    __shared__ int   sscan[256];
    __shared__ int   stot;
    int k = blockIdx.x;
    int t = threadIdx.x;
    if (t < NBA) lcur[t] = 0;
    __syncthreads();
    int lo = k * CH, hi = min(E, lo + CH);
    for (int i = lo + t; i < hi; i += 256) {
        int u  = eu[i];
        int it = ei[i] + U;
        atomicAdd(&lcur[u >> BS_LOG], 1);
        atomicAdd(&lcur[it >> BS_LOG], 1);
    }
    __syncthreads();
    int c = (t < NB) ? lcur[t] : 0;
    sscan[t] = c;
    __syncthreads();
    for (int d = 1; d < 256; d <<= 1) {
        int v = (t >= d) ? sscan[t - d] : 0;
        __syncthreads();
        sscan[t] += v;
        __syncthreads();
    }
    if (t < NB) {
        int st = sscan[t] - c;                    // local segment start
        lcur[t] = st;                             // reuse as cursor
        ldif[t] = t * CAP + bh[k * NBA + t] - st; // slot -> global dst delta
    }
    if (t == 255) stot = sscan[255];
    __syncthreads();
    for (int i = lo + t; i < hi; i += 256) {
        int u  = eu[i];
        int it = ei[i] + U;
        unsigned vb = __float_as_uint(ev[i]);
        int b1 = u >> BS_LOG;
        int s1 = atomicAdd(&lcur[b1], 1);
        sent[s1] = make_uint2((unsigned)((u & 1023) | (it << 10)), vb);
        sdst[s1] = ldif[b1] + s1;
        int b2 = it >> BS_LOG;
        int s2 = atomicAdd(&lcur[b2], 1);
        sent[s2] = make_uint2((unsigned)((it & 1023) | (u << 10)), vb);
        sdst[s2] = ldif[b2] + s2;
    }
    __syncthreads();
    int tot = stot;
    for (int i = t; i < tot; i += 256) {
        uint2 e = sent[i];
        gb[sdst[i]] = make_int2((int)e.x, (int)e.y);
    }
}

// One 1024-thread block per bucket (1 node per thread): hist + float-deg
// accumulate in LDS, 1024-wide LDS scan of padded (align4) per-node sizes,
// write offs/cnt/dinv/dsq, zero-fill pad slots, bucket-local CSR scatter.
__global__ __launch_bounds__(1024) void k_bucket_csr(
        const int2* __restrict__ gb, const int* __restrict__ total,
        const int* __restrict__ bbase,
        int* __restrict__ offs, int* __restrict__ cnt,
        float* __restrict__ dinv, float* __restrict__ dsq,
        int2* __restrict__ csr, int N, int CAP) {
    __shared__ int   hist[1024];
    __shared__ float degf[1024];
    __shared__ int   offl[1024];
    __shared__ int   scan[1024];
    int b = blockIdx.x;
    int t = threadIdx.x;
    int n0 = b << BS_LOG;
    int nbc = min(1024, N - n0);
    int cb = min(total[b], CAP);
    int base = bbase[b];
    const int2* gbb = gb + (size_t)b * CAP;

    hist[t] = 0;
    degf[t] = 0.f;
    __syncthreads();
    for (int i = t; i < cb; i += 1024) {
        int2 e = gbb[i];
        int rl = e.x & 1023;
        atomicAdd(&hist[rl], 1);
        atomicAdd(&degf[rl], __int_as_float(e.y));
    }
    __syncthreads();
    int h = hist[t];
    int h4 = (h + 3) & ~3;           // padded per-node size
    scan[t] = h4;
    __syncthreads();
    for (int d = 1; d < 1024; d <<= 1) {
        int v = (t >= d) ? scan[t - d] : 0;
        __syncthreads();
        scan[t] += v;
        __syncthreads();
    }
    int off4 = scan[t] - h4;         // exclusive padded within-bucket offset
    offl[t] = off4;
    if (t < nbc) {
        int node = n0 + t;
        offs[node] = base + off4;
        cnt[node]  = h;
        float s = degf[t];
        bool pos = (s > 0.0f);
        dinv[node] = pos ? rsqrtf(fmaxf(s, 1e-12f)) : 0.0f;
        dsq[node]  = pos ? sqrtf(s) : 0.0f;
        for (int p = h; p < h4; ++p)                 // zero-fill pad slots
            csr[base + off4 + p] = make_int2(0, 0);
    }
    hist[t] = 0;                     // reuse as per-node cursor
    __syncthreads();
    for (int i = t; i < cb; i += 1024) {
        int2 e = gbb[i];
        int rl = e.x & 1023;
        int col = (int)(((unsigned)e.x) >> 10);
        int tk = atomicAdd(&hist[rl], 1);
        csr[base + offl[rl] + tk] = make_int2(col, e.y);
    }
}

// g0 = bf16(dinv * concat(emb)). 4 elems/thread.
__global__ void k_init(const float4* __restrict__ emb_u, const float4* __restrict__ emb_i,
                       const float* __restrict__ dinv,
                       ushort4* __restrict__ g0, int U16, int N16) {
    int i = blockIdx.x * blockDim.x + threadIdx.x;
    if (i >= N16) return;
    float4 v = (i < U16) ? emb_u[i] : emb_i[i - U16];
    float d = dinv[i >> 4];
    ushort4 o;
    o.x = f32_to_bf16(v.x * d);
    o.y = f32_to_bf16(v.y * d);
    o.z = f32_to_bf16(v.z * d);
    o.w = f32_to_bf16(v.w * d);
    g0[i] = o;
}

// GROUP-PER-ROW: 8 lanes per row (q = lane&7 holds dims 8q..8q+7), 8 rows
// per wave. csr rows padded to 4-entry multiples, 32B-aligned -> inner loop
// is branch-free: 2x dwordx4 csr loads (broadcast within group) + 4
// independent row gathers per 4 neighbors; next csr block prefetched under
// the FMAs. Pad entries {col=0,w=0} gather row 0 and add 0 (no-op).
__global__ __launch_bounds__(256) void k_layer(
        const uint4* __restrict__ gin, uint4* __restrict__ gout,
        const float* __restrict__ dinv,
        const int* __restrict__ offs, const int* __restrict__ cnt,
        const int2* __restrict__ csr, int N) {
    int gtid = blockIdx.x * blockDim.x + threadIdx.x;
    int row = gtid >> 3;
    unsigned q = threadIdx.x & 7;
    if (row >= N) return;
    int base = offs[row];
    int c = cnt[row];
    int nIter = (c + 3) >> 2;        // 4 neighbors per iteration

    float a0 = 0.f, a1 = 0.f, a2 = 0.f, a3 = 0.f;
    float a4 = 0.f, a5 = 0.f, a6 = 0.f, a7 = 0.f;

    const uint4* ep4 = (const uint4*)(csr + base);   // 32B-aligned
    uint4 E0 = make_uint4(0, 0, 0, 0), E1 = E0;
    if (nIter > 0) { E0 = ep4[0]; E1 = ep4[1]; }     // {c0,w0,c1,w1},{c2,w2,c3,w3}

    for (int i = 0; i < nIter; ++i) {
        uint4 G0 = gin[(E0.x << 3) | q];
        uint4 G1 = gin[(E0.z << 3) | q];
        uint4 G2 = gin[(E1.x << 3) | q];
        uint4 G3 = gin[(E1.z << 3) | q];
        // prefetch next csr block (reads <=32B past row end; slack allocated)
        uint4 P0 = ep4[2 * i + 2];
        uint4 P1 = ep4[2 * i + 3];
        float w0 = __uint_as_float(E0.y);
        float w1 = __uint_as_float(E0.w);
        float w2 = __uint_as_float(E1.y);
        float w3 = __uint_as_float(E1.w);
        a0 += w0 * bf16_lo(G0.x); a1 += w0 * bf16_hi(G0.x);
        a2 += w0 * bf16_lo(G0.y); a3 += w0 * bf16_hi(G0.y);
        a4 += w0 * bf16_lo(G0.z); a5 += w0 * bf16_hi(G0.z);
        a6 += w0 * bf16_lo(G0.w); a7 += w0 * bf16_hi(G0.w);
        a0 += w1 * bf16_lo(G1.x); a1 += w1 * bf16_hi(G1.x);
        a2 += w1 * bf16_lo(G1.y); a3 += w1 * bf16_hi(G1.y);
        a4 += w1 * bf16_lo(G1.z); a5 += w1 * bf16_hi(G1.z);
        a6 += w1 * bf16_lo(G1.w); a7 += w1 * bf16_hi(G1.w);
        a0 += w2 * bf16_lo(G2.x); a1 += w2 * bf16_hi(G2.x);
        a2 += w2 * bf16_lo(G2.y); a3 += w2 * bf16_hi(G2.y);
        a4 += w2 * bf16_lo(G2.z); a5 += w2 * bf16_hi(G2.z);
        a6 += w2 * bf16_lo(G2.w); a7 += w2 * bf16_hi(G2.w);
        a0 += w3 * bf16_lo(G3.x); a1 += w3 * bf16_hi(G3.x);
        a2 += w3 * bf16_lo(G3.y); a3 += w3 * bf16_hi(G3.y);
        a4 += w3 * bf16_lo(G3.z); a5 += w3 * bf16_hi(G3.z);
        a6 += w3 * bf16_lo(G3.w); a7 += w3 * bf16_hi(G3.w);
        E0 = P0; E1 = P1;
    }

    float dr = dinv[row];
    float d2 = dr * dr;
    uint4 o;
    o.x = (unsigned int)f32_to_bf16(d2 * a0) | ((unsigned int)f32_to_bf16(d2 * a1) << 16);
    o.y = (unsigned int)f32_to_bf16(d2 * a2) | ((unsigned int)f32_to_bf16(d2 * a3) << 16);
    o.z = (unsigned int)f32_to_bf16(d2 * a4) | ((unsigned int)f32_to_bf16(d2 * a5) << 16);
    o.w = (unsigned int)f32_to_bf16(d2 * a6) | ((unsigned int)f32_to_bf16(d2 * a7) << 16);
    gout[((unsigned)row << 3) | q] = o;
}

// out (float4 units): [Uf | Upass | If | Ipass]; Uf/If = (e0 + sum dsq*g_l)/25.
__global__ void k_final(const float4* __restrict__ emb_u, const float4* __restrict__ emb_i,
                        const ushort4* __restrict__ g1, const ushort4* __restrict__ g2,
                        const ushort4* __restrict__ g3, const ushort4* __restrict__ g4,
                        const float* __restrict__ dsq,
                        float4* __restrict__ out, int U16, int I16) {
    int i = blockIdx.x * blockDim.x + threadIdx.x;
    int total = 2 * U16 + 2 * I16;
    if (i >= total) return;
    const float s = 1.0f / 25.0f;
    float4 r;
    if (i < U16 || (i >= 2 * U16 && i < 2 * U16 + I16)) {
        int gi, node;
        float4 e0;
        if (i < U16) { gi = i; node = i >> 4; e0 = emb_u[i]; }
        else { int j = i - 2 * U16; gi = U16 + j; node = (U16 >> 4) + (j >> 4); e0 = emb_i[j]; }
        float d = dsq[node];
        ushort4 a = g1[gi], b = g2[gi], cc = g3[gi], dd = g4[gi];
        float gx = bf16_to_f32(a.x) + bf16_to_f32(b.x) + bf16_to_f32(cc.x) + bf16_to_f32(dd.x);
        float gy = bf16_to_f32(a.y) + bf16_to_f32(b.y) + bf16_to_f32(cc.y) + bf16_to_f32(dd.y);
        float gz = bf16_to_f32(a.z) + bf16_to_f32(b.z) + bf16_to_f32(cc.z) + bf16_to_f32(dd.z);
        float gw = bf16_to_f32(a.w) + bf16_to_f32(b.w) + bf16_to_f32(cc.w) + bf16_to_f32(dd.w);
        r = make_float4((e0.x + d * gx) * s, (e0.y + d * gy) * s,
                        (e0.z + d * gz) * s, (e0.w + d * gw) * s);
    } else if (i < 2 * U16) {
        r = emb_u[i - U16];
    } else {
        r = emb_i[i - 2 * U16 - I16];
    }
    out[i] = r;
}

extern "C" void kernel_launch(void* const* d_in, const int* in_sizes, int n_in,
                              void* d_out, int out_size, void* d_ws, size_t ws_size,
                              hipStream_t stream) {
    const float* emb_u = (const float*)d_in[0];
    const float* emb_i = (const float*)d_in[1];
    const int*   eu    = (const int*)d_in[2];
    const int*   ei    = (const int*)d_in[3];
    const float* ev    = (const float*)d_in[4];

    const int U = in_sizes[0] / 64;
    const int I = in_sizes[1] / 64;
    const int N = U + I;
    const int E = in_sizes[2];
    const int DE = 2 * E;

    const int NB = (N + 1023) >> BS_LOG;   // 147 buckets for N = 150000 (<= NBA)
    const int CH = (E + KB - 1) / KB;      // edges per count/scatter block

    // ---- workspace carve ----
    char* base = (char*)d_ws;
    size_t off = 0;
    int*   offs  = (int*)  (base + off); off = align_up(off + (size_t)N * 4, 256);
    int*   cnt   = (int*)  (base + off); off = align_up(off + (size_t)N * 4, 256);
    float* dinv  = (float*)(base + off); off = align_up(off + (size_t)N * 4, 256);
    float* dsq   = (float*)(base + off); off = align_up(off + (size_t)N * 4, 256);
    int*   bh    = (int*)  (base + off); off = align_up(off + (size_t)NBA * KB * 4, 256);
    int*   total = (int*)  (base + off); off = align_up(off + (size_t)NBA * 4, 256);
    int*   bbase = (int*)  (base + off); off = align_up(off + (size_t)NBA * 4, 256);
    // padded CSR: DE entries + per-bucket (align4 + 3072) slack + prefetch slack
    int2*  csr   = (int2*) (base + off);
    off = align_up(off + ((size_t)DE + (size_t)NBA * 3080 + 32) * 8, 256);
    unsigned short* g[5];
    for (int l = 0; l < 5; ++l) {
        g[l] = (unsigned short*)(base + off);
        off = align_up(off + (size_t)N * 64 * 2, 256);
    }
    (void)ws_size;

    // Bucket staging aliases g[1..4] (dead until layer 0 writes g[1]).
    int2* gb = (int2*)g[1];
    size_t gcap = (size_t)4 * N * 128;                 // bytes available at g[1]
    int CAP = (int)(gcap / ((size_t)NB * 8));          // per-bucket entry cap
    if (CAP > 65536) CAP = 65536;                      // ~2.3x max expected bucket load

    const int B = 256;
    k_bucket_count  <<<KB, B, 0, stream>>>(eu, ei, bh, U, E, NB, CH);
    k_scan_blocks   <<<NB, B, 0, stream>>>(bh, total, NB);
    k_scan_buckets  <<<1,  B, 0, stream>>>(total, bbase, NB);
    k_bucket_scatter<<<KB, B, 0, stream>>>(eu, ei, ev, bh, gb, U, E, NB, CH, CAP);
    k_bucket_csr    <<<NB, 1024, 0, stream>>>(gb, total, bbase, offs, cnt, dinv, dsq, csr, N, CAP);

    const int U16 = U * 16, I16 = I * 16, N16 = N * 16;
    k_init<<<(N16 + B - 1) / B, B, 0, stream>>>((const float4*)emb_u, (const float4*)emb_i,
                                                dinv, (ushort4*)g[0], U16, N16);

    for (int layer = 0; layer < 4; ++layer) {
        int threads = N * 8;               // 8 lanes per row
        k_layer<<<(threads + B - 1) / B, B, 0, stream>>>(
            (const uint4*)g[layer], (uint4*)g[layer + 1], dinv, offs, cnt, csr, N);
    }

    int totalv4 = 2 * U16 + 2 * I16;
    k_final<<<(totalv4 + B - 1) / B, B, 0, stream>>>(
        (const float4*)emb_u, (const float4*)emb_i,
        (const ushort4*)g[1], (const ushort4*)g[2], (const ushort4*)g[3], (const ushort4*)g[4],
        dsq, (float4*)d_out, U16, I16);
}